// Round 8
// baseline (400.844 us; speedup 1.0000x reference)
//
#include <hip/hip_runtime.h>
#include <hip/hip_bf16.h>
#include <stdint.h>

#define NPTS 16384
#define CDIM 256
#define HEADS 8
#define KNBR 8
#define HIDD 512
#define OUTD 64
#define NEMB 64
#define RHIDD 16

typedef _Float16 half8 __attribute__((ext_vector_type(8)));
typedef float f32x4 __attribute__((ext_vector_type(4)));

__device__ __forceinline__ float gelu_tanh(float v) {
    float v3 = v * v * v;
    return 0.5f * v * (1.0f + tanhf(0.79788456080286535588f * (v + 0.044715f * v3)));
}

__device__ __forceinline__ void gload16(const void* g, void* l) {
    __builtin_amdgcn_global_load_lds((const __attribute__((address_space(1))) void*)g,
                                     (__attribute__((address_space(3))) void*)l, 16, 0, 0);
}

// ---------------------------------------------------------------------------
// Split-fp16 MFMA GEMM (QKV+gate only now), 128x128 tile, 4 waves.
// 3-term (AhiBhi + AhiBlo + AloBhi); per 32-true-K chunk hi|lo staged
// interleaved in one 128-B LDS row, one barrier pair, three MFMA passes.
// cols<1536 -> fp32 QKV (ld 1536); cols 1536..1543 -> G[N,8]
// ---------------------------------------------------------------------------
__launch_bounds__(256)
__global__ void gemm_qkv(const _Float16* __restrict__ A2, const _Float16* __restrict__ B2,
                         float* __restrict__ QKV, float* __restrict__ G) {
    __shared__ __align__(16) char lds[32768];

    const int tid = threadIdx.x;
    const int l = tid & 63, w = tid >> 6;
    const int g = l >> 4, r = l & 15;
    const int wr = w >> 1, wc = w & 1;
    const int m0 = blockIdx.y * 128;
    const int n0 = blockIdx.x * 128;
    const int ldA = 512;                            // 2*Kpad, Kpad=256
    const int srow = l >> 3;
    const int sl = (l & 7) ^ srow;
    const int scol = (sl & 3) * 8 + ((sl >= 4) ? 256 : 0);
    const int swz = (l & 7) << 4;
    const int aBase = (wr * 64 + r) * 128;
    const int bBase = 16384 + (wc * 64 + r) * 128;
    const int koh = (g << 4) ^ swz;
    const int kol = (64 | (g << 4)) ^ swz;

    f32x4 acc[4][4] = {};

    const _Float16* aS = A2 + (size_t)m0 * ldA + scol;
    const _Float16* bS = B2 + (size_t)n0 * ldA + scol;

    for (int t = 0; t < 8; ++t) {
        const int kk = t * 32;
        #pragma unroll
        for (int cc = 0; cc < 4; ++cc) {
            int ch = w * 4 + cc;
            int row = ch * 8 + srow;
            gload16(aS + (size_t)row * ldA + kk, lds + ch * 1024);
            gload16(bS + (size_t)row * ldA + kk, lds + 16384 + ch * 1024);
        }
        __syncthreads();
        half8 ah[4], bh[4], xf[4];
        #pragma unroll
        for (int i = 0; i < 4; ++i) ah[i] = *(const half8*)(lds + aBase + i * 2048 + koh);
        #pragma unroll
        for (int j = 0; j < 4; ++j) bh[j] = *(const half8*)(lds + bBase + j * 2048 + koh);
        #pragma unroll
        for (int i = 0; i < 4; ++i)
            #pragma unroll
            for (int j = 0; j < 4; ++j)
                acc[i][j] = __builtin_amdgcn_mfma_f32_16x16x32_f16(ah[i], bh[j], acc[i][j], 0, 0, 0);
        #pragma unroll
        for (int j = 0; j < 4; ++j) xf[j] = *(const half8*)(lds + bBase + j * 2048 + kol);
        #pragma unroll
        for (int i = 0; i < 4; ++i)
            #pragma unroll
            for (int j = 0; j < 4; ++j)
                acc[i][j] = __builtin_amdgcn_mfma_f32_16x16x32_f16(ah[i], xf[j], acc[i][j], 0, 0, 0);
        #pragma unroll
        for (int i = 0; i < 4; ++i) xf[i] = *(const half8*)(lds + aBase + i * 2048 + kol);
        #pragma unroll
        for (int i = 0; i < 4; ++i)
            #pragma unroll
            for (int j = 0; j < 4; ++j)
                acc[i][j] = __builtin_amdgcn_mfma_f32_16x16x32_f16(xf[i], bh[j], acc[i][j], 0, 0, 0);
        __syncthreads();
    }

    #pragma unroll
    for (int i = 0; i < 4; ++i) {
        #pragma unroll
        for (int j = 0; j < 4; ++j) {
            const int gcol = n0 + wc * 64 + j * 16 + r;
            #pragma unroll
            for (int q = 0; q < 4; ++q) {
                const int row = m0 + wr * 64 + i * 16 + g * 4 + q;
                float v = acc[i][j][q];
                if (gcol < 1536) {
                    QKV[(size_t)row * 1536 + gcol] = v;
                } else if (gcol < 1544) {
                    G[(size_t)row * 8 + (gcol - 1536)] = v;
                }
            }
        }
    }
}

// ---------------------------------------------------------------------------
// MEGA TAIL: one kernel per 32-row strip (512 blocks, 1 block/CU):
//   phase 0: h1 = DynTanh1(x + att @ Wo)           -> h1L (LDS, staged fmt)
//   tail:    h2[512:576] = DynTanh2(x[:, :20])|0   -> h2full kt 16,17
//   phase B: h2[0:512] = DynTanh2(gelu(h1 @ Wlin)) -> h2full (LDS, staged fmt)
//   phase C: z = tanh(gelu(h2 @ Wout + bout))
//   VQ:      argmin vs codebook, write zq rows + atomic loss partial
// All GEMM phases: dbuf staging + counted vmcnt + raw barrier (round-6 proven).
// Staged LDS format per 32-k window: [row/8 chunks][8 rows][128 B], byte
// (within row) = logical ^ ((row&7)<<4); logical 0-63 = hi halfs, 64-127 = lo.
// Per-element FP chains identical to the previous separate kernels -> z bitwise
// identical -> VQ argmin identical.
// ---------------------------------------------------------------------------
__launch_bounds__(256)
__global__ void mega_tail(const _Float16* __restrict__ att2,
                          const _Float16* __restrict__ wo2,
                          const _Float16* __restrict__ wlin2,
                          const _Float16* __restrict__ wout2,
                          const float* __restrict__ x,
                          const float* __restrict__ alpha1p, const float* __restrict__ gamma1,
                          const float* __restrict__ beta1, const float* __restrict__ blin,
                          const float* __restrict__ alpha2p, const float* __restrict__ gamma2,
                          const float* __restrict__ beta2, const float* __restrict__ bout,
                          const float* __restrict__ cb,
                          float* __restrict__ outZ, float* __restrict__ outLoss) {
    // R0 @0      (32 KB): h1L (8 kt-windows x 4 KB); later zL/cbL/psum
    // R1 @32768  (72 KB): phase-0 B dbuf (2x36 KB) -> h2full (18 windows x 4 KB)
    // R2 @106496 (16 KB): phase B/C stage dbuf (2x8 KB)
    __shared__ __align__(16) char lds[122880];
    char* const h1L = lds;
    char* const R1  = lds + 32768;
    char* const R2  = lds + 106496;

    const int tid = threadIdx.x;
    const int l = tid & 63, w = tid >> 6;
    const int g = l >> 4, r = l & 15;
    const int wr = w >> 1, wc = w & 1;
    const int m0 = blockIdx.x * 32;
    const int srow = l >> 3;
    const int sl = (l & 7) ^ srow;
    const int scol576 = (sl & 3) * 8 + ((sl >= 4) ? 576 : 0);
    const int scol256 = (sl & 3) * 8 + ((sl >= 4) ? 256 : 0);
    const int swz = (r & 7) << 4;
    const int koh = (g << 4) ^ swz;
    const int kol = (64 | (g << 4)) ^ swz;
    const float a1 = alpha1p[0], a2 = alpha2p[0];

    // ---------------- phase 0: h1 strip (32x256) ----------------
    f32x4 acc0[8] = {};
    {
        auto stage0 = [&](int buf, int kt) {
            char* d = R1 + buf * 36864;
            const int kk = kt * 32;
            gload16(att2 + (size_t)(m0 + w * 8 + srow) * 1152 + kk + scol576, d + w * 1024);
            #pragma unroll
            for (int i = 0; i < 8; ++i) {
                int ch = w * 8 + i;
                gload16(wo2 + (size_t)(ch * 8 + srow) * 1152 + kk + scol576,
                        d + 4096 + ch * 1024);
            }
        };
        stage0(0, 0);
        for (int kt = 0; kt < 18; ++kt) {
            const int cur = kt & 1;
            if (kt + 1 < 18) {
                stage0(cur ^ 1, kt + 1);
                asm volatile("s_waitcnt vmcnt(9)" ::: "memory");
            } else {
                asm volatile("s_waitcnt vmcnt(0)" ::: "memory");
            }
            __builtin_amdgcn_s_barrier();
            __builtin_amdgcn_sched_barrier(0);
            const char* d = R1 + cur * 36864;
            const int arow = wr * 16 + r;
            const char* aAddr = d + (arow >> 3) * 1024 + (arow & 7) * 128;
            half8 a_h = *(const half8*)(aAddr + koh);
            half8 a_l = *(const half8*)(aAddr + kol);
            #pragma unroll
            for (int jf = 0; jf < 8; ++jf) {
                const int brow = wc * 128 + jf * 16 + r;
                const char* bAddr = d + 4096 + (brow >> 3) * 1024 + (brow & 7) * 128;
                half8 b_h = *(const half8*)(bAddr + koh);
                half8 b_l = *(const half8*)(bAddr + kol);
                acc0[jf] = __builtin_amdgcn_mfma_f32_16x16x32_f16(a_h, b_h, acc0[jf], 0, 0, 0);
                acc0[jf] = __builtin_amdgcn_mfma_f32_16x16x32_f16(a_h, b_l, acc0[jf], 0, 0, 0);
                acc0[jf] = __builtin_amdgcn_mfma_f32_16x16x32_f16(a_l, b_h, acc0[jf], 0, 0, 0);
            }
            __builtin_amdgcn_s_barrier();
        }
    }
    // phase-0 epilogue: DynTanh1 -> h1L (staged+swizzled)
    #pragma unroll
    for (int jf = 0; jf < 8; ++jf) {
        #pragma unroll
        for (int q = 0; q < 4; ++q) {
            const int row = wr * 16 + g * 4 + q;
            const int col = wc * 128 + jf * 16 + r;
            float v = acc0[jf][q] + x[(size_t)(m0 + row) * CDIM + col];
            v = tanhf(a1 * v) * gamma1[col] + beta1[col];
            _Float16 hi = (_Float16)v;
            _Float16 lo = (_Float16)(v - (float)hi);
            const int ktw = col >> 5, kloc = col & 31;
            const int Lhi = ((kloc >> 3) << 4) | ((kloc & 7) << 1);
            const int sw = (row & 7) << 4;
            char* base = h1L + ktw * 4096 + (row >> 3) * 1024 + (row & 7) * 128;
            *(_Float16*)(base + (Lhi ^ sw)) = hi;
            *(_Float16*)(base + ((Lhi | 64) ^ sw)) = lo;
        }
    }
    // tail fill: h2 cols 512..575 (DynTanh2(x[:, :20]) | zeros) -> windows 16,17
    {
        const int rw = tid >> 3, c8 = tid & 7;
        #pragma unroll
        for (int u = 0; u < 8; ++u) {
            const int col = c8 * 8 + u;
            float v = 0.f;
            if (col < 20)
                v = tanhf(a2 * x[(size_t)(m0 + rw) * CDIM + col]) * gamma2[512 + col] + beta2[512 + col];
            _Float16 hi = (_Float16)v;
            _Float16 lo = (_Float16)(v - (float)hi);
            const int ktw = 16 + (col >> 5), kloc = col & 31;
            const int Lhi = ((kloc >> 3) << 4) | ((kloc & 7) << 1);
            const int sw = (rw & 7) << 4;
            char* base = R1 + ktw * 4096 + (rw >> 3) * 1024 + (rw & 7) * 128;
            *(_Float16*)(base + (Lhi ^ sw)) = hi;
            *(_Float16*)(base + ((Lhi | 64) ^ sw)) = lo;
        }
    }
    __syncthreads();

    // ---------------- phase B: h2[:, :512] (8 col-chunks of 64) ----------------
    {
        f32x4 accB[2] = {};
        accB[0] = (f32x4){0.f, 0.f, 0.f, 0.f};
        accB[1] = (f32x4){0.f, 0.f, 0.f, 0.f};
        auto stageB = [&](int it) {
            const int c2 = it >> 3, kt2 = it & 7;
            char* d = R2 + (it & 1) * 8192;
            #pragma unroll
            for (int i = 0; i < 2; ++i) {
                int ch = w * 2 + i;
                gload16(wlin2 + (size_t)(c2 * 64 + ch * 8 + srow) * 512 + kt2 * 32 + scol256,
                        d + ch * 1024);
            }
        };
        stageB(0);
        for (int it = 0; it < 64; ++it) {
            if (it + 1 < 64) {
                stageB(it + 1);
                asm volatile("s_waitcnt vmcnt(2)" ::: "memory");
            } else {
                asm volatile("s_waitcnt vmcnt(0)" ::: "memory");
            }
            __builtin_amdgcn_s_barrier();
            __builtin_amdgcn_sched_barrier(0);
            const int kt = it & 7;
            const char* d = R2 + (it & 1) * 8192;
            const int arow = wr * 16 + r;
            const char* aAddr = h1L + kt * 4096 + (arow >> 3) * 1024 + (arow & 7) * 128;
            half8 a_h = *(const half8*)(aAddr + koh);
            half8 a_l = *(const half8*)(aAddr + kol);
            #pragma unroll
            for (int jf = 0; jf < 2; ++jf) {
                const int brow = wc * 32 + jf * 16 + r;
                const char* bAddr = d + (brow >> 3) * 1024 + (brow & 7) * 128;
                half8 b_h = *(const half8*)(bAddr + koh);
                half8 b_l = *(const half8*)(bAddr + kol);
                accB[jf] = __builtin_amdgcn_mfma_f32_16x16x32_f16(a_h, b_h, accB[jf], 0, 0, 0);
                accB[jf] = __builtin_amdgcn_mfma_f32_16x16x32_f16(a_h, b_l, accB[jf], 0, 0, 0);
                accB[jf] = __builtin_amdgcn_mfma_f32_16x16x32_f16(a_l, b_h, accB[jf], 0, 0, 0);
            }
            if ((it & 7) == 7) {
                const int c2 = it >> 3;
                #pragma unroll
                for (int jf = 0; jf < 2; ++jf) {
                    #pragma unroll
                    for (int q = 0; q < 4; ++q) {
                        const int row = wr * 16 + g * 4 + q;
                        const int colg = c2 * 64 + wc * 32 + jf * 16 + r;
                        float v = gelu_tanh(accB[jf][q] + blin[colg]);
                        v = tanhf(a2 * v) * gamma2[colg] + beta2[colg];
                        _Float16 hi = (_Float16)v;
                        _Float16 lo = (_Float16)(v - (float)hi);
                        const int ktw = colg >> 5, kloc = colg & 31;
                        const int Lhi = ((kloc >> 3) << 4) | ((kloc & 7) << 1);
                        const int sw = (row & 7) << 4;
                        char* base = R1 + ktw * 4096 + (row >> 3) * 1024 + (row & 7) * 128;
                        *(_Float16*)(base + (Lhi ^ sw)) = hi;
                        *(_Float16*)(base + ((Lhi | 64) ^ sw)) = lo;
                    }
                    accB[jf] = (f32x4){0.f, 0.f, 0.f, 0.f};
                }
            }
            __builtin_amdgcn_s_barrier();
        }
    }
    __syncthreads();

    // ---------------- phase C: z (32x64) over K=576 ----------------
    f32x4 accC[2] = {};
    {
        auto stageC = [&](int kt) {
            char* d = R2 + (kt & 1) * 8192;
            #pragma unroll
            for (int i = 0; i < 2; ++i) {
                int ch = w * 2 + i;
                gload16(wout2 + (size_t)(ch * 8 + srow) * 1152 + kt * 32 + scol576,
                        d + ch * 1024);
            }
        };
        stageC(0);
        for (int kt = 0; kt < 18; ++kt) {
            if (kt + 1 < 18) {
                stageC(kt + 1);
                asm volatile("s_waitcnt vmcnt(2)" ::: "memory");
            } else {
                asm volatile("s_waitcnt vmcnt(0)" ::: "memory");
            }
            __builtin_amdgcn_s_barrier();
            __builtin_amdgcn_sched_barrier(0);
            const char* d = R2 + (kt & 1) * 8192;
            const int arow = wr * 16 + r;
            const char* aAddr = R1 + kt * 4096 + (arow >> 3) * 1024 + (arow & 7) * 128;
            half8 a_h = *(const half8*)(aAddr + koh);
            half8 a_l = *(const half8*)(aAddr + kol);
            #pragma unroll
            for (int jf = 0; jf < 2; ++jf) {
                const int brow = wc * 32 + jf * 16 + r;
                const char* bAddr = d + (brow >> 3) * 1024 + (brow & 7) * 128;
                half8 b_h = *(const half8*)(bAddr + koh);
                half8 b_l = *(const half8*)(bAddr + kol);
                accC[jf] = __builtin_amdgcn_mfma_f32_16x16x32_f16(a_h, b_h, accC[jf], 0, 0, 0);
                accC[jf] = __builtin_amdgcn_mfma_f32_16x16x32_f16(a_h, b_l, accC[jf], 0, 0, 0);
                accC[jf] = __builtin_amdgcn_mfma_f32_16x16x32_f16(a_l, b_h, accC[jf], 0, 0, 0);
            }
            __builtin_amdgcn_s_barrier();
        }
    }

    // ---------------- VQ ----------------
    float* zL   = (float*)lds;             // [32][68]
    float* cbL  = (float*)(lds + 8704);    // [64][68], col 64 = ||cb||^2
    float* psum = (float*)(lds + 26112);   // [32]
    #pragma unroll
    for (int jf = 0; jf < 2; ++jf) {
        #pragma unroll
        for (int q = 0; q < 4; ++q) {
            const int row = wr * 16 + g * 4 + q;
            const int col = wc * 32 + jf * 16 + r;
            zL[row * 68 + col] = tanhf(gelu_tanh(accC[jf][q] + bout[col]));
        }
    }
    for (int i = tid; i < NEMB * OUTD / 4; i += 256) {
        float4 v = ((const float4*)cb)[i];
        int e = (i * 4) >> 6, c0 = (i * 4) & 63;
        cbL[e * 68 + c0 + 0] = v.x; cbL[e * 68 + c0 + 1] = v.y;
        cbL[e * 68 + c0 + 2] = v.z; cbL[e * 68 + c0 + 3] = v.w;
    }
    __syncthreads();
    if (tid < 64) {
        float cc = 0.f;
        #pragma unroll
        for (int d = 0; d < 64; ++d) { float cv = cbL[tid * 68 + d]; cc += cv * cv; }
        cbL[tid * 68 + 64] = cc;
    }
    __syncthreads();

    const int row = tid >> 3, part = tid & 7;
    float best = 1e30f;
    int bidx = 0;
    for (int e = part * 8; e < part * 8 + 8; ++e) {
        float dot = 0.f;
        #pragma unroll
        for (int d = 0; d < 64; ++d) dot += zL[row * 68 + d] * cbL[e * 68 + d];
        float sc = cbL[e * 68 + 64] - 2.f * dot;
        if (sc < best) { best = sc; bidx = e; }
    }
    #pragma unroll
    for (int m = 1; m <= 4; m <<= 1) {
        float ob = __shfl_xor(best, m, 64);
        int oi = __shfl_xor(bidx, m, 64);
        if (ob < best || (ob == best && oi < bidx)) { best = ob; bidx = oi; }
    }
    float lsum = 0.f;
    #pragma unroll
    for (int u = 0; u < 8; ++u) {
        const int col = part * 8 + u;
        float cv = cbL[bidx * 68 + col];
        outZ[(size_t)(m0 + row) * 64 + col] = cv;
        float df = zL[row * 68 + col] - cv;
        lsum += df * df;
    }
    lsum += __shfl_xor(lsum, 1, 64);
    lsum += __shfl_xor(lsum, 2, 64);
    lsum += __shfl_xor(lsum, 4, 64);
    if (part == 0) psum[row] = lsum;
    __syncthreads();
    if (tid < 32) {
        float v = psum[tid];
        #pragma unroll
        for (int m = 1; m < 32; m <<= 1) v += __shfl_xor(v, m, 64);
        if (tid == 0)
            atomicAdd(outLoss, v * (0.25f / ((float)NPTS * (float)OUTD)));
    }
}

// ---------------------------------------------------------------------------
// merged prep: x2 split, wqkv2 (incl gate cols + zero pad), wo2T, wlin2T,
// wout2T; also zero-inits outLoss
// ---------------------------------------------------------------------------
#define R0SZ (NPTS * CDIM)
#define S1 (1664 * 256)
#define S2 (256 * 576)
#define S3 (512 * 256)
#define S4 (64 * 576)
__global__ void prep(const float* __restrict__ x,
                     const float* __restrict__ Wq, const float* __restrict__ Wk,
                     const float* __restrict__ Wv, const float* __restrict__ w_gate,
                     const float* __restrict__ Wo, const float* __restrict__ Wlin,
                     const float* __restrict__ Wout,
                     _Float16* __restrict__ x2, _Float16* __restrict__ wqkv2,
                     _Float16* __restrict__ wo2, _Float16* __restrict__ wlin2,
                     _Float16* __restrict__ wout2, float* __restrict__ outLoss) {
    if (blockIdx.x == 0 && threadIdx.x == 0) *outLoss = 0.f;
    for (int idx = blockIdx.x * 256 + threadIdx.x; idx < R0SZ + S1 + S2 + S3 + S4;
         idx += gridDim.x * 256) {
        float v; _Float16* dst; size_t o0, o1;
        if (idx < R0SZ) {
            int n = idx >> 8, cc = idx & 255;
            v = x[idx];
            dst = x2; o0 = (size_t)n * 512 + cc; o1 = o0 + 256;
        } else if (idx < R0SZ + S1) {
            int t = idx - R0SZ;
            int j = t >> 8, k = t & 255;
            if (j < 1536) {
                int jm = j & 511;
                const float* W = (j < 512) ? Wq : (j < 1024) ? Wk : Wv;
                v = W[(size_t)k * 512 + jm];
            } else if (j < 1544) {
                v = w_gate[(size_t)k * 8 + (j - 1536)];
            } else {
                v = 0.f;
            }
            dst = wqkv2; o0 = (size_t)j * 512 + k; o1 = o0 + 256;
        } else if (idx < R0SZ + S1 + S2) {
            int t = idx - R0SZ - S1;
            int j = t / 576, k = t - j * 576;
            v = (k < 520) ? Wo[(size_t)k * 256 + j] : 0.f;
            dst = wo2; o0 = (size_t)j * 1152 + k; o1 = o0 + 576;
        } else if (idx < R0SZ + S1 + S2 + S3) {
            int t = idx - R0SZ - S1 - S2;
            int j = t >> 8, k = t & 255;
            v = Wlin[(size_t)k * 512 + j];
            dst = wlin2; o0 = (size_t)j * 512 + k; o1 = o0 + 256;
        } else {
            int t = idx - R0SZ - S1 - S2 - S3;
            int j = t / 576, k = t - j * 576;
            v = (k < 532) ? Wout[(size_t)k * 64 + j] : 0.f;
            dst = wout2; o0 = (size_t)j * 1152 + k; o1 = o0 + 576;
        }
        _Float16 hi = (_Float16)v, lo = (_Float16)(v - (float)hi);
        dst[o0] = hi; dst[o1] = lo;
    }
}

// ---------------------------------------------------------------------------
// Attention (measured-best form, unchanged): one wave per node, lane = h*8+c.
// ---------------------------------------------------------------------------
__launch_bounds__(256)
__global__ void attn_kernel(const float* __restrict__ QKV, const float* __restrict__ G,
                            const float* __restrict__ coors, const int* __restrict__ nbr,
                            const float* __restrict__ Wr1, const float* __restrict__ br1,
                            const float* __restrict__ Wr2, const float* __restrict__ br2,
                            _Float16* __restrict__ att2) {
    __shared__ float unitL[4][8][3];
    __shared__ float distL[4][8];
    __shared__ float radH[4][8][16];

    const int tid = threadIdx.x;
    const int w = tid >> 6;
    const int lane = tid & 63;
    const int n = blockIdx.x * 4 + w;
    const int h = lane >> 3;
    const int c = lane & 7;

    int jreg[KNBR];
    #pragma unroll
    for (int k = 0; k < KNBR; ++k) jreg[k] = nbr[(size_t)n * KNBR + k];

    if (lane < KNBR) {
        int jj = jreg[lane];
        float rx = coors[(size_t)jj * 3 + 0] - coors[(size_t)n * 3 + 0];
        float ry = coors[(size_t)jj * 3 + 1] - coors[(size_t)n * 3 + 1];
        float rz = coors[(size_t)jj * 3 + 2] - coors[(size_t)n * 3 + 2];
        float d = sqrtf(rx * rx + ry * ry + rz * rz + 1e-8f);
        float inv = 1.0f / d;
        distL[w][lane] = d;
        unitL[w][lane][0] = rx * inv;
        unitL[w][lane][1] = ry * inv;
        unitL[w][lane][2] = rz * inv;
    }

    const float4* qp = (const float4*)(QKV + (size_t)n * 1536 + lane * 8);
    float4 q0 = qp[0], q1 = qp[1];
    float p[KNBR];
    #pragma unroll
    for (int k = 0; k < KNBR; ++k) {
        const float4* kp = (const float4*)(QKV + (size_t)jreg[k] * 1536 + 512 + lane * 8);
        float4 k0 = kp[0], k1 = kp[1];
        p[k] = q0.x * k0.x + q0.y * k0.y + q0.z * k0.z + q0.w * k0.w
             + q1.x * k1.x + q1.y * k1.y + q1.z * k1.z + q1.w * k1.w;
    }
    #pragma unroll
    for (int m = 1; m <= 4; m <<= 1) {
        #pragma unroll
        for (int k = 0; k < KNBR; ++k) p[k] += __shfl_xor(p[k], m, 64);
    }
    __syncthreads();

    #pragma unroll
    for (int rr = 0; rr < 2; ++rr) {
        int idx = lane + rr * 64;
        int k = idx >> 4, i = idx & 15;
        float hv = distL[w][k] * Wr1[i] + br1[i];
        radH[w][k][i] = gelu_tanh(hv);
    }
    __syncthreads();

    float lg[KNBR];
    float b2v = br2[h];
    #pragma unroll
    for (int k = 0; k < KNBR; ++k) {
        float rad = b2v;
        #pragma unroll
        for (int i = 0; i < RHIDD; ++i) rad += radH[w][k][i] * Wr2[i * HEADS + h];
        lg[k] = p[k] * 0.125f + rad;
        if (!(distL[w][k] <= 10.0f)) lg[k] = -1e9f;
    }
    float mx = lg[0];
    #pragma unroll
    for (int k = 1; k < KNBR; ++k) mx = fmaxf(mx, lg[k]);
    float a[KNBR];
    float s = 0.f;
    #pragma unroll
    for (int k = 0; k < KNBR; ++k) { a[k] = expf(lg[k] - mx); s += a[k]; }
    float is = 1.0f / s;
    #pragma unroll
    for (int k = 0; k < KNBR; ++k) a[k] *= is;

    float vx = 0.f, vy = 0.f, vz = 0.f;
    #pragma unroll
    for (int k = 0; k < KNBR; ++k) {
        float gg = G[(size_t)jreg[k] * HEADS + h];
        float ag = a[k] * gg;
        vx += ag * unitL[w][k][0];
        vy += ag * unitL[w][k][1];
        vz += ag * unitL[w][k][2];
    }
    float vn = sqrtf(vx * vx + vy * vy + vz * vz + 1e-8f);

    float4 o0 = {0.f, 0.f, 0.f, 0.f}, o1 = {0.f, 0.f, 0.f, 0.f};
    #pragma unroll
    for (int k = 0; k < KNBR; ++k) {
        const float4* vp = (const float4*)(QKV + (size_t)jreg[k] * 1536 + 1024 + lane * 8);
        float4 v0 = vp[0], v1 = vp[1];
        float ak = a[k];
        o0.x += ak * v0.x; o0.y += ak * v0.y; o0.z += ak * v0.z; o0.w += ak * v0.w;
        o1.x += ak * v1.x; o1.y += ak * v1.y; o1.z += ak * v1.z; o1.w += ak * v1.w;
    }

    float ov[8] = {o0.x, o0.y, o0.z, o0.w, o1.x, o1.y, o1.z, o1.w};
    half8 hi8, lo8;
    #pragma unroll
    for (int t = 0; t < 8; ++t) {
        _Float16 hi = (_Float16)ov[t];
        hi8[t] = hi;
        lo8[t] = (_Float16)(ov[t] - (float)hi);
    }
    *(half8*)(att2 + (size_t)n * 1152 + lane * 8) = hi8;
    *(half8*)(att2 + (size_t)n * 1152 + 576 + lane * 8) = lo8;
    if (c == 0) {
        _Float16 hi = (_Float16)vn, lo = (_Float16)(vn - (float)hi);
        att2[(size_t)n * 1152 + 512 + h] = hi;
        att2[(size_t)n * 1152 + 576 + 512 + h] = lo;
    }
    if (lane < 56) {
        att2[(size_t)n * 1152 + 520 + lane] = (_Float16)0.f;
        att2[(size_t)n * 1152 + 1096 + lane] = (_Float16)0.f;
    }
}

// ---------------------------------------------------------------------------
extern "C" void kernel_launch(void* const* d_in, const int* in_sizes, int n_in,
                              void* d_out, int out_size, void* d_ws, size_t ws_size,
                              hipStream_t stream) {
    const float* x      = (const float*)d_in[0];
    const float* coors  = (const float*)d_in[1];
    const int*   nbr    = (const int*)  d_in[2];
    const float* Wq     = (const float*)d_in[3];
    const float* Wk     = (const float*)d_in[4];
    const float* Wv     = (const float*)d_in[5];
    const float* w_gate = (const float*)d_in[6];
    const float* Wr1    = (const float*)d_in[7];
    const float* br1    = (const float*)d_in[8];
    const float* Wr2    = (const float*)d_in[9];
    const float* br2    = (const float*)d_in[10];
    const float* Wo     = (const float*)d_in[11];
    const float* alpha1 = (const float*)d_in[12];
    const float* gamma1 = (const float*)d_in[13];
    const float* beta1  = (const float*)d_in[14];
    const float* Wlin   = (const float*)d_in[15];
    const float* blin   = (const float*)d_in[16];
    const float* alpha2 = (const float*)d_in[17];
    const float* gamma2 = (const float*)d_in[18];
    const float* beta2  = (const float*)d_in[19];
    const float* Wout   = (const float*)d_in[20];
    const float* bout   = (const float*)d_in[21];
    const float* cb     = (const float*)d_in[22];

    char* wsb = (char*)d_ws;
    float*    QKV   = (float*)   (wsb + 0);          // 100.66 MB, dead after attn
    _Float16* att2  = (_Float16*)(wsb + 100663296);  // 37.75 MB
    _Float16* x2    = (_Float16*)(wsb + 138412032);  // 16.78 MB
    _Float16* wqkv2 = (_Float16*)(wsb + 155189248);  // 1.70 MB
    _Float16* wo2   = (_Float16*)(wsb + 156893184);  // 0.59 MB
    _Float16* wlin2 = (_Float16*)(wsb + 157483008);  // 0.52 MB
    _Float16* wout2 = (_Float16*)(wsb + 158007296);  // 0.15 MB
    float*    G     = (float*)   (wsb + 158154752);  // 0.52 MB

    float* outZ    = (float*)d_out;
    float* outLoss = outZ + (size_t)NPTS * OUTD;

    dim3 blk(256);

    // prep (x split + all weight splits + gate cols + loss zero-init)
    prep<<<dim3(2048), blk, 0, stream>>>(x, Wq, Wk, Wv, w_gate, Wo, Wlin, Wout,
                                         x2, wqkv2, wo2, wlin2, wout2, outLoss);
    // QKV+gate = x @ [Wq|Wk|Wv|w_gate]
    gemm_qkv<<<dim3(13, 128), blk, 0, stream>>>(x2, wqkv2, QKV, G);
    // attention
    attn_kernel<<<dim3(NPTS / 4), blk, 0, stream>>>(QKV, G, coors, nbr, Wr1, br1, Wr2, br2, att2);
    // fused tail: Wo -> DynTanh1 -> Wlin -> gelu/DynTanh2 -> Wout -> tanh -> VQ
    mega_tail<<<dim3(NPTS / 32), blk, 0, stream>>>(att2, wo2, wlin2, wout2, x,
        alpha1, gamma1, beta1, blin, alpha2, gamma2, beta2, bout, cb, outZ, outLoss);
}

// Round 9
// 376.869 us; speedup vs baseline: 1.0636x; 1.0636x over previous
//
#include <hip/hip_runtime.h>
#include <hip/hip_bf16.h>
#include <stdint.h>

#define NPTS 16384
#define CDIM 256
#define HEADS 8
#define KNBR 8
#define HIDD 512
#define OUTD 64
#define NEMB 64
#define RHIDD 16

typedef _Float16 half8 __attribute__((ext_vector_type(8)));
typedef float f32x4 __attribute__((ext_vector_type(4)));

__device__ __forceinline__ float gelu_tanh(float v) {
    float v3 = v * v * v;
    return 0.5f * v * (1.0f + tanhf(0.79788456080286535588f * (v + 0.044715f * v3)));
}

__device__ __forceinline__ void gload16(const void* g, void* l) {
    __builtin_amdgcn_global_load_lds((const __attribute__((address_space(1))) void*)g,
                                     (__attribute__((address_space(3))) void*)l, 16, 0, 0);
}

// ---------------------------------------------------------------------------
// QKV+gate GEMM (measured-best round-7/8 form): 128x128 tile, 4 waves,
// 3-pass split-fp16 (AhiBhi+AhiBlo+AloBhi), hi|lo interleaved staging.
// ---------------------------------------------------------------------------
__launch_bounds__(256)
__global__ void gemm_qkv(const _Float16* __restrict__ A2, const _Float16* __restrict__ B2,
                         float* __restrict__ QKV, float* __restrict__ G) {
    __shared__ __align__(16) char lds[32768];

    const int tid = threadIdx.x;
    const int l = tid & 63, w = tid >> 6;
    const int g = l >> 4, r = l & 15;
    const int wr = w >> 1, wc = w & 1;
    const int m0 = blockIdx.y * 128;
    const int n0 = blockIdx.x * 128;
    const int ldA = 512;
    const int srow = l >> 3;
    const int sl = (l & 7) ^ srow;
    const int scol = (sl & 3) * 8 + ((sl >= 4) ? 256 : 0);
    const int swz = (l & 7) << 4;
    const int aBase = (wr * 64 + r) * 128;
    const int bBase = 16384 + (wc * 64 + r) * 128;
    const int koh = (g << 4) ^ swz;
    const int kol = (64 | (g << 4)) ^ swz;

    f32x4 acc[4][4] = {};

    const _Float16* aS = A2 + (size_t)m0 * ldA + scol;
    const _Float16* bS = B2 + (size_t)n0 * ldA + scol;

    for (int t = 0; t < 8; ++t) {
        const int kk = t * 32;
        #pragma unroll
        for (int cc = 0; cc < 4; ++cc) {
            int ch = w * 4 + cc;
            int row = ch * 8 + srow;
            gload16(aS + (size_t)row * ldA + kk, lds + ch * 1024);
            gload16(bS + (size_t)row * ldA + kk, lds + 16384 + ch * 1024);
        }
        __syncthreads();
        half8 ah[4], bh[4], xf[4];
        #pragma unroll
        for (int i = 0; i < 4; ++i) ah[i] = *(const half8*)(lds + aBase + i * 2048 + koh);
        #pragma unroll
        for (int j = 0; j < 4; ++j) bh[j] = *(const half8*)(lds + bBase + j * 2048 + koh);
        #pragma unroll
        for (int i = 0; i < 4; ++i)
            #pragma unroll
            for (int j = 0; j < 4; ++j)
                acc[i][j] = __builtin_amdgcn_mfma_f32_16x16x32_f16(ah[i], bh[j], acc[i][j], 0, 0, 0);
        #pragma unroll
        for (int j = 0; j < 4; ++j) xf[j] = *(const half8*)(lds + bBase + j * 2048 + kol);
        #pragma unroll
        for (int i = 0; i < 4; ++i)
            #pragma unroll
            for (int j = 0; j < 4; ++j)
                acc[i][j] = __builtin_amdgcn_mfma_f32_16x16x32_f16(ah[i], xf[j], acc[i][j], 0, 0, 0);
        #pragma unroll
        for (int i = 0; i < 4; ++i) xf[i] = *(const half8*)(lds + aBase + i * 2048 + kol);
        #pragma unroll
        for (int i = 0; i < 4; ++i)
            #pragma unroll
            for (int j = 0; j < 4; ++j)
                acc[i][j] = __builtin_amdgcn_mfma_f32_16x16x32_f16(xf[i], bh[j], acc[i][j], 0, 0, 0);
        __syncthreads();
    }

    #pragma unroll
    for (int i = 0; i < 4; ++i) {
        #pragma unroll
        for (int j = 0; j < 4; ++j) {
            const int gcol = n0 + wc * 64 + j * 16 + r;
            #pragma unroll
            for (int q = 0; q < 4; ++q) {
                const int row = m0 + wr * 64 + i * 16 + g * 4 + q;
                float v = acc[i][j][q];
                if (gcol < 1536) {
                    QKV[(size_t)row * 1536 + gcol] = v;
                } else if (gcol < 1544) {
                    G[(size_t)row * 8 + (gcol - 1536)] = v;
                }
            }
        }
    }
}

// ---------------------------------------------------------------------------
// Tail GEMM, 64x128 tile (2-3 blocks/CU co-residency — the round-8 lesson),
// 4 waves side by side (wave w owns cols w*32..w*32+31, all 64 rows).
// Double-buffered staging (2x24KB) + counted vmcnt(6) + raw barriers.
// Same kt-order / 3-pass accumulation chain per output element as the
// measured round-7 kernels -> bitwise-identical z.
// EPI 1: +res(x), DynTanh1 -> split h1s (stride 512); cols<64 also write the
//        h2 tail (x[:, :20] DynTanh2 + zero pad) into aux (=h2s, stride 1152)
// EPI 2: gelu(+bias) then DynTanh2 -> split h2s (stride 1152)
// ---------------------------------------------------------------------------
template <int EPI>
__launch_bounds__(256)
__global__ void gemm_tail64(const _Float16* __restrict__ A2, const _Float16* __restrict__ B2,
                            int Kpad, int KT, void* __restrict__ Cout,
                            const float* __restrict__ bias,
                            const float* __restrict__ res,
                            const float* __restrict__ alphap,
                            const float* __restrict__ gamma,
                            const float* __restrict__ beta,
                            const float* __restrict__ a2p,
                            const float* __restrict__ g2,
                            const float* __restrict__ b2,
                            void* __restrict__ aux) {
    __shared__ __align__(16) char lds[49152];      // 2 x (8KB A + 16KB B)

    const int tid = threadIdx.x;
    const int l = tid & 63, w = tid >> 6;
    const int g = l >> 4, r = l & 15;
    const int m0 = blockIdx.y * 64;
    const int n0 = blockIdx.x * 128;
    const int ldA = 2 * Kpad;
    const int srow = l >> 3;
    const int sl = (l & 7) ^ srow;
    const int scol = (sl & 3) * 8 + ((sl >= 4) ? Kpad : 0);
    const int swz = (l & 7) << 4;
    const int koh = (g << 4) ^ swz;
    const int kol = (64 | (g << 4)) ^ swz;

    f32x4 acc[4][2] = {};

    const _Float16* aS = A2 + (size_t)m0 * ldA + scol;
    const _Float16* bS = B2 + (size_t)n0 * ldA + scol;

    auto stage = [&](int buf, int t) {
        const int kk = t * 32;
        char* d = lds + buf * 24576;
        #pragma unroll
        for (int cc = 0; cc < 2; ++cc) {           // A: 8 chunks / 4 waves
            int ch = w * 2 + cc;
            gload16(aS + (size_t)(ch * 8 + srow) * ldA + kk, d + ch * 1024);
        }
        #pragma unroll
        for (int cc = 0; cc < 4; ++cc) {           // B: 16 chunks / 4 waves
            int ch = w * 4 + cc;
            gload16(bS + (size_t)(ch * 8 + srow) * ldA + kk, d + 8192 + ch * 1024);
        }
    };

    stage(0, 0);
    for (int t = 0; t < KT; ++t) {
        const int cur = t & 1;
        if (t + 1 < KT) {
            stage(cur ^ 1, t + 1);
            asm volatile("s_waitcnt vmcnt(6)" ::: "memory");
        } else {
            asm volatile("s_waitcnt vmcnt(0)" ::: "memory");
        }
        __builtin_amdgcn_s_barrier();
        __builtin_amdgcn_sched_barrier(0);
        const char* Lb = lds + cur * 24576;
        half8 ah[4], bh[2], xf[4];
        #pragma unroll
        for (int i = 0; i < 4; ++i) ah[i] = *(const half8*)(Lb + (i * 16 + r) * 128 + koh);
        #pragma unroll
        for (int j = 0; j < 2; ++j) bh[j] = *(const half8*)(Lb + 8192 + (w * 32 + j * 16 + r) * 128 + koh);
        // pass 0: Ahi * Bhi
        #pragma unroll
        for (int i = 0; i < 4; ++i)
            #pragma unroll
            for (int j = 0; j < 2; ++j)
                acc[i][j] = __builtin_amdgcn_mfma_f32_16x16x32_f16(ah[i], bh[j], acc[i][j], 0, 0, 0);
        // pass 1: Ahi * Blo
        #pragma unroll
        for (int j = 0; j < 2; ++j) xf[j] = *(const half8*)(Lb + 8192 + (w * 32 + j * 16 + r) * 128 + kol);
        #pragma unroll
        for (int i = 0; i < 4; ++i)
            #pragma unroll
            for (int j = 0; j < 2; ++j)
                acc[i][j] = __builtin_amdgcn_mfma_f32_16x16x32_f16(ah[i], xf[j], acc[i][j], 0, 0, 0);
        // pass 2: Alo * Bhi
        #pragma unroll
        for (int i = 0; i < 4; ++i) xf[i] = *(const half8*)(Lb + (i * 16 + r) * 128 + kol);
        #pragma unroll
        for (int i = 0; i < 4; ++i)
            #pragma unroll
            for (int j = 0; j < 2; ++j)
                acc[i][j] = __builtin_amdgcn_mfma_f32_16x16x32_f16(xf[i], bh[j], acc[i][j], 0, 0, 0);
        __builtin_amdgcn_s_barrier();
    }

    const float alp = alphap[0];
    #pragma unroll
    for (int i = 0; i < 4; ++i) {
        #pragma unroll
        for (int j = 0; j < 2; ++j) {
            const int gcol = n0 + w * 32 + j * 16 + r;
            #pragma unroll
            for (int q = 0; q < 4; ++q) {
                const int row = m0 + i * 16 + g * 4 + q;
                float v = acc[i][j][q];
                if (EPI == 1) {
                    v += res[(size_t)row * CDIM + gcol];
                    v = tanhf(alp * v) * gamma[gcol] + beta[gcol];
                    _Float16 hi = (_Float16)v;
                    _Float16 lo = (_Float16)(v - (float)hi);
                    _Float16* H = (_Float16*)Cout;
                    H[(size_t)row * 512 + gcol] = hi;
                    H[(size_t)row * 512 + 256 + gcol] = lo;
                    if (gcol < 64) {
                        int tc = 512 + gcol;
                        float tv = 0.f;
                        if (gcol < 20)
                            tv = tanhf(a2p[0] * res[(size_t)row * CDIM + gcol]) * g2[tc] + b2[tc];
                        _Float16 thi = (_Float16)tv;
                        _Float16 tlo = (_Float16)(tv - (float)thi);
                        _Float16* T = (_Float16*)aux;
                        T[(size_t)row * 1152 + tc] = thi;
                        T[(size_t)row * 1152 + 576 + tc] = tlo;
                    }
                } else {
                    v = gelu_tanh(v + bias[gcol]);
                    v = tanhf(alp * v) * gamma[gcol] + beta[gcol];
                    _Float16 hi = (_Float16)v;
                    _Float16 lo = (_Float16)(v - (float)hi);
                    _Float16* H = (_Float16*)Cout;
                    H[(size_t)row * 1152 + gcol] = hi;
                    H[(size_t)row * 1152 + 576 + gcol] = lo;
                }
            }
        }
    }
}

// ---------------------------------------------------------------------------
// Wout GEMM (64x64 tile) with fused VQ + loss atomic (round-7 measured form).
// ---------------------------------------------------------------------------
__launch_bounds__(256)
__global__ void gemm_out_vq(const _Float16* __restrict__ A2, const _Float16* __restrict__ B2,
                            const float* __restrict__ bout, const float* __restrict__ cb,
                            float* __restrict__ outZ, float* __restrict__ outLoss) {
    __shared__ __align__(16) char lds[34816];
    __shared__ float psum[64];
    float* zL  = (float*)lds;
    float* cbL = (float*)(lds + 17408);

    const int tid = threadIdx.x;
    const int l = tid & 63, w = tid >> 6;
    const int g = l >> 4, r = l & 15;
    const int wr = w >> 1, wc = w & 1;
    const int m0 = blockIdx.x * 64;
    const int Kpad = 576;
    const int ldA = 1152;
    const int srow = l >> 3;
    const int sl = (l & 7) ^ srow;
    const int scol = (sl & 3) * 8 + ((sl >= 4) ? Kpad : 0);
    const int swz = (l & 7) << 4;
    const int aBase = (wr * 32 + r) * 128;
    const int bBase = 8192 + (wc * 32 + r) * 128;
    const int koh = (g << 4) ^ swz;
    const int kol = (64 | (g << 4)) ^ swz;

    f32x4 acc[2][2] = {};

    const _Float16* aS = A2 + (size_t)m0 * ldA + scol;
    const _Float16* bS = B2 + scol;

    auto stage = [&](int buf, int t) {
        const int kk = t * 32;
        char* d0 = lds + buf * 16384;
        #pragma unroll
        for (int cc = 0; cc < 2; ++cc) {
            int ch = w * 2 + cc;
            int row = ch * 8 + srow;
            gload16(aS + (size_t)row * ldA + kk, d0 + ch * 1024);
            gload16(bS + (size_t)row * ldA + kk, d0 + 8192 + ch * 1024);
        }
    };

    stage(0, 0);
    for (int t = 0; t < 18; ++t) {
        const int cur = t & 1;
        if (t + 1 < 18) {
            stage(cur ^ 1, t + 1);
            asm volatile("s_waitcnt vmcnt(4)" ::: "memory");
        } else {
            asm volatile("s_waitcnt vmcnt(0)" ::: "memory");
        }
        __builtin_amdgcn_s_barrier();
        __builtin_amdgcn_sched_barrier(0);
        const char* Lb = lds + cur * 16384;
        half8 ah[2], bh[2], xf[2];
        #pragma unroll
        for (int i = 0; i < 2; ++i) ah[i] = *(const half8*)(Lb + aBase + i * 2048 + koh);
        #pragma unroll
        for (int j = 0; j < 2; ++j) bh[j] = *(const half8*)(Lb + bBase + j * 2048 + koh);
        #pragma unroll
        for (int i = 0; i < 2; ++i)
            #pragma unroll
            for (int j = 0; j < 2; ++j)
                acc[i][j] = __builtin_amdgcn_mfma_f32_16x16x32_f16(ah[i], bh[j], acc[i][j], 0, 0, 0);
        #pragma unroll
        for (int j = 0; j < 2; ++j) xf[j] = *(const half8*)(Lb + bBase + j * 2048 + kol);
        #pragma unroll
        for (int i = 0; i < 2; ++i)
            #pragma unroll
            for (int j = 0; j < 2; ++j)
                acc[i][j] = __builtin_amdgcn_mfma_f32_16x16x32_f16(ah[i], xf[j], acc[i][j], 0, 0, 0);
        #pragma unroll
        for (int i = 0; i < 2; ++i) xf[i] = *(const half8*)(Lb + aBase + i * 2048 + kol);
        #pragma unroll
        for (int i = 0; i < 2; ++i)
            #pragma unroll
            for (int j = 0; j < 2; ++j)
                acc[i][j] = __builtin_amdgcn_mfma_f32_16x16x32_f16(xf[i], bh[j], acc[i][j], 0, 0, 0);
        __builtin_amdgcn_s_barrier();
    }

    #pragma unroll
    for (int i = 0; i < 2; ++i) {
        #pragma unroll
        for (int j = 0; j < 2; ++j) {
            int col = wc * 32 + j * 16 + r;
            #pragma unroll
            for (int q = 0; q < 4; ++q) {
                int rl = wr * 32 + i * 16 + g * 4 + q;
                zL[rl * 68 + col] = tanhf(gelu_tanh(acc[i][j][q] + bout[col]));
            }
        }
    }
    for (int i = tid; i < NEMB * OUTD / 4; i += 256) {
        float4 v = ((const float4*)cb)[i];
        int e = (i * 4) >> 6, c0 = (i * 4) & 63;
        cbL[e * 68 + c0 + 0] = v.x; cbL[e * 68 + c0 + 1] = v.y;
        cbL[e * 68 + c0 + 2] = v.z; cbL[e * 68 + c0 + 3] = v.w;
    }
    __syncthreads();
    if (tid < 64) {
        float cc = 0.f;
        #pragma unroll
        for (int d = 0; d < 64; ++d) { float cv = cbL[tid * 68 + d]; cc += cv * cv; }
        cbL[tid * 68 + 64] = cc;
    }
    __syncthreads();

    const int row = tid >> 2, part = tid & 3;
    float best = 1e30f;
    int bidx = 0;
    for (int e = part * 16; e < part * 16 + 16; ++e) {
        float dot = 0.f;
        #pragma unroll
        for (int d = 0; d < 64; ++d) dot += zL[row * 68 + d] * cbL[e * 68 + d];
        float sc = cbL[e * 68 + 64] - 2.f * dot;
        if (sc < best) { best = sc; bidx = e; }
    }
    #pragma unroll
    for (int m = 1; m <= 2; m <<= 1) {
        float ob = __shfl_xor(best, m, 64);
        int oi = __shfl_xor(bidx, m, 64);
        if (ob < best || (ob == best && oi < bidx)) { best = ob; bidx = oi; }
    }
    const int grow = m0 + row;
    float lsum = 0.f;
    #pragma unroll
    for (int u = 0; u < 16; ++u) {
        float cv = cbL[bidx * 68 + part * 16 + u];
        outZ[(size_t)grow * 64 + part * 16 + u] = cv;
        float df = zL[row * 68 + part * 16 + u] - cv;
        lsum += df * df;
    }
    lsum += __shfl_xor(lsum, 1, 64);
    lsum += __shfl_xor(lsum, 2, 64);
    if (part == 0) psum[row] = lsum;
    __syncthreads();
    if (tid < 64) {
        float v = psum[tid];
        #pragma unroll
        for (int m = 1; m < 64; m <<= 1) v += __shfl_xor(v, m, 64);
        if (tid == 0)
            atomicAdd(outLoss, v * (0.25f / ((float)NPTS * (float)OUTD)));
    }
}

// ---------------------------------------------------------------------------
// merged prep: x2 split, wqkv2 (incl gate cols + zero pad), wo2T, wlin2T,
// wout2T; also zero-inits outLoss
// ---------------------------------------------------------------------------
#define R0SZ (NPTS * CDIM)
#define S1 (1664 * 256)
#define S2 (256 * 576)
#define S3 (512 * 256)
#define S4 (64 * 576)
__global__ void prep(const float* __restrict__ x,
                     const float* __restrict__ Wq, const float* __restrict__ Wk,
                     const float* __restrict__ Wv, const float* __restrict__ w_gate,
                     const float* __restrict__ Wo, const float* __restrict__ Wlin,
                     const float* __restrict__ Wout,
                     _Float16* __restrict__ x2, _Float16* __restrict__ wqkv2,
                     _Float16* __restrict__ wo2, _Float16* __restrict__ wlin2,
                     _Float16* __restrict__ wout2, float* __restrict__ outLoss) {
    if (blockIdx.x == 0 && threadIdx.x == 0) *outLoss = 0.f;
    for (int idx = blockIdx.x * 256 + threadIdx.x; idx < R0SZ + S1 + S2 + S3 + S4;
         idx += gridDim.x * 256) {
        float v; _Float16* dst; size_t o0, o1;
        if (idx < R0SZ) {
            int n = idx >> 8, cc = idx & 255;
            v = x[idx];
            dst = x2; o0 = (size_t)n * 512 + cc; o1 = o0 + 256;
        } else if (idx < R0SZ + S1) {
            int t = idx - R0SZ;
            int j = t >> 8, k = t & 255;
            if (j < 1536) {
                int jm = j & 511;
                const float* W = (j < 512) ? Wq : (j < 1024) ? Wk : Wv;
                v = W[(size_t)k * 512 + jm];
            } else if (j < 1544) {
                v = w_gate[(size_t)k * 8 + (j - 1536)];
            } else {
                v = 0.f;
            }
            dst = wqkv2; o0 = (size_t)j * 512 + k; o1 = o0 + 256;
        } else if (idx < R0SZ + S1 + S2) {
            int t = idx - R0SZ - S1;
            int j = t / 576, k = t - j * 576;
            v = (k < 520) ? Wo[(size_t)k * 256 + j] : 0.f;
            dst = wo2; o0 = (size_t)j * 1152 + k; o1 = o0 + 576;
        } else if (idx < R0SZ + S1 + S2 + S3) {
            int t = idx - R0SZ - S1 - S2;
            int j = t >> 8, k = t & 255;
            v = Wlin[(size_t)k * 512 + j];
            dst = wlin2; o0 = (size_t)j * 512 + k; o1 = o0 + 256;
        } else {
            int t = idx - R0SZ - S1 - S2 - S3;
            int j = t / 576, k = t - j * 576;
            v = (k < 532) ? Wout[(size_t)k * 64 + j] : 0.f;
            dst = wout2; o0 = (size_t)j * 1152 + k; o1 = o0 + 576;
        }
        _Float16 hi = (_Float16)v, lo = (_Float16)(v - (float)hi);
        dst[o0] = hi; dst[o1] = lo;
    }
}

// ---------------------------------------------------------------------------
// Attention (measured-best form, unchanged): one wave per node, lane = h*8+c.
// ---------------------------------------------------------------------------
__launch_bounds__(256)
__global__ void attn_kernel(const float* __restrict__ QKV, const float* __restrict__ G,
                            const float* __restrict__ coors, const int* __restrict__ nbr,
                            const float* __restrict__ Wr1, const float* __restrict__ br1,
                            const float* __restrict__ Wr2, const float* __restrict__ br2,
                            _Float16* __restrict__ att2) {
    __shared__ float unitL[4][8][3];
    __shared__ float distL[4][8];
    __shared__ float radH[4][8][16];

    const int tid = threadIdx.x;
    const int w = tid >> 6;
    const int lane = tid & 63;
    const int n = blockIdx.x * 4 + w;
    const int h = lane >> 3;
    const int c = lane & 7;

    int jreg[KNBR];
    #pragma unroll
    for (int k = 0; k < KNBR; ++k) jreg[k] = nbr[(size_t)n * KNBR + k];

    if (lane < KNBR) {
        int jj = jreg[lane];
        float rx = coors[(size_t)jj * 3 + 0] - coors[(size_t)n * 3 + 0];
        float ry = coors[(size_t)jj * 3 + 1] - coors[(size_t)n * 3 + 1];
        float rz = coors[(size_t)jj * 3 + 2] - coors[(size_t)n * 3 + 2];
        float d = sqrtf(rx * rx + ry * ry + rz * rz + 1e-8f);
        float inv = 1.0f / d;
        distL[w][lane] = d;
        unitL[w][lane][0] = rx * inv;
        unitL[w][lane][1] = ry * inv;
        unitL[w][lane][2] = rz * inv;
    }

    const float4* qp = (const float4*)(QKV + (size_t)n * 1536 + lane * 8);
    float4 q0 = qp[0], q1 = qp[1];
    float p[KNBR];
    #pragma unroll
    for (int k = 0; k < KNBR; ++k) {
        const float4* kp = (const float4*)(QKV + (size_t)jreg[k] * 1536 + 512 + lane * 8);
        float4 k0 = kp[0], k1 = kp[1];
        p[k] = q0.x * k0.x + q0.y * k0.y + q0.z * k0.z + q0.w * k0.w
             + q1.x * k1.x + q1.y * k1.y + q1.z * k1.z + q1.w * k1.w;
    }
    #pragma unroll
    for (int m = 1; m <= 4; m <<= 1) {
        #pragma unroll
        for (int k = 0; k < KNBR; ++k) p[k] += __shfl_xor(p[k], m, 64);
    }
    __syncthreads();

    #pragma unroll
    for (int rr = 0; rr < 2; ++rr) {
        int idx = lane + rr * 64;
        int k = idx >> 4, i = idx & 15;
        float hv = distL[w][k] * Wr1[i] + br1[i];
        radH[w][k][i] = gelu_tanh(hv);
    }
    __syncthreads();

    float lg[KNBR];
    float b2v = br2[h];
    #pragma unroll
    for (int k = 0; k < KNBR; ++k) {
        float rad = b2v;
        #pragma unroll
        for (int i = 0; i < RHIDD; ++i) rad += radH[w][k][i] * Wr2[i * HEADS + h];
        lg[k] = p[k] * 0.125f + rad;
        if (!(distL[w][k] <= 10.0f)) lg[k] = -1e9f;
    }
    float mx = lg[0];
    #pragma unroll
    for (int k = 1; k < KNBR; ++k) mx = fmaxf(mx, lg[k]);
    float a[KNBR];
    float s = 0.f;
    #pragma unroll
    for (int k = 0; k < KNBR; ++k) { a[k] = expf(lg[k] - mx); s += a[k]; }
    float is = 1.0f / s;
    #pragma unroll
    for (int k = 0; k < KNBR; ++k) a[k] *= is;

    float vx = 0.f, vy = 0.f, vz = 0.f;
    #pragma unroll
    for (int k = 0; k < KNBR; ++k) {
        float gg = G[(size_t)jreg[k] * HEADS + h];
        float ag = a[k] * gg;
        vx += ag * unitL[w][k][0];
        vy += ag * unitL[w][k][1];
        vz += ag * unitL[w][k][2];
    }
    float vn = sqrtf(vx * vx + vy * vy + vz * vz + 1e-8f);

    float4 o0 = {0.f, 0.f, 0.f, 0.f}, o1 = {0.f, 0.f, 0.f, 0.f};
    #pragma unroll
    for (int k = 0; k < KNBR; ++k) {
        const float4* vp = (const float4*)(QKV + (size_t)jreg[k] * 1536 + 1024 + lane * 8);
        float4 v0 = vp[0], v1 = vp[1];
        float ak = a[k];
        o0.x += ak * v0.x; o0.y += ak * v0.y; o0.z += ak * v0.z; o0.w += ak * v0.w;
        o1.x += ak * v1.x; o1.y += ak * v1.y; o1.z += ak * v1.z; o1.w += ak * v1.w;
    }

    float ov[8] = {o0.x, o0.y, o0.z, o0.w, o1.x, o1.y, o1.z, o1.w};
    half8 hi8, lo8;
    #pragma unroll
    for (int t = 0; t < 8; ++t) {
        _Float16 hi = (_Float16)ov[t];
        hi8[t] = hi;
        lo8[t] = (_Float16)(ov[t] - (float)hi);
    }
    *(half8*)(att2 + (size_t)n * 1152 + lane * 8) = hi8;
    *(half8*)(att2 + (size_t)n * 1152 + 576 + lane * 8) = lo8;
    if (c == 0) {
        _Float16 hi = (_Float16)vn, lo = (_Float16)(vn - (float)hi);
        att2[(size_t)n * 1152 + 512 + h] = hi;
        att2[(size_t)n * 1152 + 576 + 512 + h] = lo;
    }
    if (lane < 56) {
        att2[(size_t)n * 1152 + 520 + lane] = (_Float16)0.f;
        att2[(size_t)n * 1152 + 1096 + lane] = (_Float16)0.f;
    }
}

// ---------------------------------------------------------------------------
extern "C" void kernel_launch(void* const* d_in, const int* in_sizes, int n_in,
                              void* d_out, int out_size, void* d_ws, size_t ws_size,
                              hipStream_t stream) {
    const float* x      = (const float*)d_in[0];
    const float* coors  = (const float*)d_in[1];
    const int*   nbr    = (const int*)  d_in[2];
    const float* Wq     = (const float*)d_in[3];
    const float* Wk     = (const float*)d_in[4];
    const float* Wv     = (const float*)d_in[5];
    const float* w_gate = (const float*)d_in[6];
    const float* Wr1    = (const float*)d_in[7];
    const float* br1    = (const float*)d_in[8];
    const float* Wr2    = (const float*)d_in[9];
    const float* br2    = (const float*)d_in[10];
    const float* Wo     = (const float*)d_in[11];
    const float* alpha1 = (const float*)d_in[12];
    const float* gamma1 = (const float*)d_in[13];
    const float* beta1  = (const float*)d_in[14];
    const float* Wlin   = (const float*)d_in[15];
    const float* blin   = (const float*)d_in[16];
    const float* alpha2 = (const float*)d_in[17];
    const float* gamma2 = (const float*)d_in[18];
    const float* beta2  = (const float*)d_in[19];
    const float* Wout   = (const float*)d_in[20];
    const float* bout   = (const float*)d_in[21];
    const float* cb     = (const float*)d_in[22];

    char* wsb = (char*)d_ws;
    float*    QKV   = (float*)   (wsb + 0);          // 100.66 MB, dead after attn
    _Float16* att2  = (_Float16*)(wsb + 100663296);  // 37.75 MB
    _Float16* x2    = (_Float16*)(wsb + 138412032);  // 16.78 MB
    _Float16* wqkv2 = (_Float16*)(wsb + 155189248);  // 1.70 MB
    _Float16* wo2   = (_Float16*)(wsb + 156893184);  // 0.59 MB
    _Float16* wlin2 = (_Float16*)(wsb + 157483008);  // 0.52 MB
    _Float16* wout2 = (_Float16*)(wsb + 158007296);  // 0.15 MB
    float*    G     = (float*)   (wsb + 158154752);  // 0.52 MB
    // aliases inside dead QKV region:
    _Float16* h1s   = (_Float16*)(wsb + 0);          // 16.78 MB (after attn)
    _Float16* h2s   = (_Float16*)(wsb + 20299776);   // 37.75 MB (after attn)

    float* outZ    = (float*)d_out;
    float* outLoss = outZ + (size_t)NPTS * OUTD;

    dim3 blk(256);

    // prep (x split + all weight splits + gate cols + loss zero-init)
    prep<<<dim3(2048), blk, 0, stream>>>(x, Wq, Wk, Wv, w_gate, Wo, Wlin, Wout,
                                         x2, wqkv2, wo2, wlin2, wout2, outLoss);
    // QKV+gate = x @ [Wq|Wk|Wv|w_gate]
    gemm_qkv<<<dim3(13, 128), blk, 0, stream>>>(x2, wqkv2, QKV, G);
    // attention
    attn_kernel<<<dim3(NPTS / 4), blk, 0, stream>>>(QKV, G, coors, nbr, Wr1, br1, Wr2, br2, att2);
    // h1 = DynTanh1(x + att@Wo) -> split (64x128 tiles, 512 blocks = 2/CU)
    gemm_tail64<1><<<dim3(2, 256), blk, 0, stream>>>(att2, wo2, 576, 18, h1s,
        nullptr, x, alpha1, gamma1, beta1, alpha2, gamma2, beta2, h2s);
    // h2[:, :512] = DynTanh2(gelu(h1@Wlin + blin)) -> split (1024 blocks)
    gemm_tail64<2><<<dim3(4, 256), blk, 0, stream>>>(h1s, wlin2, 256, 8, h2s,
        blin, nullptr, alpha2, gamma2, beta2, nullptr, nullptr, nullptr, nullptr);
    // z = tanh(gelu(h2@Wout + bout)) fused with VQ + loss atomic
    gemm_out_vq<<<dim3(256), blk, 0, stream>>>(h2s, wout2, bout, cb, outZ, outLoss);
}

// Round 10
// 359.229 us; speedup vs baseline: 1.1158x; 1.0491x over previous
//
#include <hip/hip_runtime.h>
#include <hip/hip_bf16.h>
#include <stdint.h>

#define NPTS 16384
#define CDIM 256
#define HEADS 8
#define KNBR 8
#define HIDD 512
#define OUTD 64
#define NEMB 64
#define RHIDD 16

typedef _Float16 half8 __attribute__((ext_vector_type(8)));
typedef float f32x4 __attribute__((ext_vector_type(4)));

__device__ __forceinline__ float gelu_tanh(float v) {
    float v3 = v * v * v;
    return 0.5f * v * (1.0f + tanhf(0.79788456080286535588f * (v + 0.044715f * v3)));
}

__device__ __forceinline__ void gload16(const void* g, void* l) {
    __builtin_amdgcn_global_load_lds((const __attribute__((address_space(1))) void*)g,
                                     (__attribute__((address_space(3))) void*)l, 16, 0, 0);
}

// ---------------------------------------------------------------------------
// QKV+gate GEMM: 128x128 tile, 4 waves, 3-pass split-fp16.
// NEW: bijective XCD swizzle (T1; 1664 blocks, 1664%8==0) so the 13 blocks
// sharing an A row-panel land on ONE XCD's L2 instead of 8.
// ---------------------------------------------------------------------------
__launch_bounds__(256)
__global__ void gemm_qkv(const _Float16* __restrict__ A2, const _Float16* __restrict__ B2,
                         float* __restrict__ QKV, float* __restrict__ G) {
    __shared__ __align__(16) char lds[32768];

    const int tid = threadIdx.x;
    const int l = tid & 63, w = tid >> 6;
    const int g = l >> 4, r = l & 15;
    const int wr = w >> 1, wc = w & 1;
    // XCD swizzle: orig dispatch order -> contiguous per-XCD chunks
    const int orig = blockIdx.y * 13 + blockIdx.x;
    const int wgid = (orig & 7) * 208 + (orig >> 3);      // 1664/8 = 208
    const int m0 = (wgid / 13) * 128;
    const int n0 = (wgid % 13) * 128;
    const int ldA = 512;
    const int srow = l >> 3;
    const int sl = (l & 7) ^ srow;
    const int scol = (sl & 3) * 8 + ((sl >= 4) ? 256 : 0);
    const int swz = (l & 7) << 4;
    const int aBase = (wr * 64 + r) * 128;
    const int bBase = 16384 + (wc * 64 + r) * 128;
    const int koh = (g << 4) ^ swz;
    const int kol = (64 | (g << 4)) ^ swz;

    f32x4 acc[4][4] = {};

    const _Float16* aS = A2 + (size_t)m0 * ldA + scol;
    const _Float16* bS = B2 + (size_t)n0 * ldA + scol;

    for (int t = 0; t < 8; ++t) {
        const int kk = t * 32;
        #pragma unroll
        for (int cc = 0; cc < 4; ++cc) {
            int ch = w * 4 + cc;
            int row = ch * 8 + srow;
            gload16(aS + (size_t)row * ldA + kk, lds + ch * 1024);
            gload16(bS + (size_t)row * ldA + kk, lds + 16384 + ch * 1024);
        }
        __syncthreads();
        half8 ah[4], bh[4], xf[4];
        #pragma unroll
        for (int i = 0; i < 4; ++i) ah[i] = *(const half8*)(lds + aBase + i * 2048 + koh);
        #pragma unroll
        for (int j = 0; j < 4; ++j) bh[j] = *(const half8*)(lds + bBase + j * 2048 + koh);
        #pragma unroll
        for (int i = 0; i < 4; ++i)
            #pragma unroll
            for (int j = 0; j < 4; ++j)
                acc[i][j] = __builtin_amdgcn_mfma_f32_16x16x32_f16(ah[i], bh[j], acc[i][j], 0, 0, 0);
        #pragma unroll
        for (int j = 0; j < 4; ++j) xf[j] = *(const half8*)(lds + bBase + j * 2048 + kol);
        #pragma unroll
        for (int i = 0; i < 4; ++i)
            #pragma unroll
            for (int j = 0; j < 4; ++j)
                acc[i][j] = __builtin_amdgcn_mfma_f32_16x16x32_f16(ah[i], xf[j], acc[i][j], 0, 0, 0);
        #pragma unroll
        for (int i = 0; i < 4; ++i) xf[i] = *(const half8*)(lds + aBase + i * 2048 + kol);
        #pragma unroll
        for (int i = 0; i < 4; ++i)
            #pragma unroll
            for (int j = 0; j < 4; ++j)
                acc[i][j] = __builtin_amdgcn_mfma_f32_16x16x32_f16(xf[i], bh[j], acc[i][j], 0, 0, 0);
        __syncthreads();
    }

    #pragma unroll
    for (int i = 0; i < 4; ++i) {
        #pragma unroll
        for (int j = 0; j < 4; ++j) {
            const int gcol = n0 + wc * 64 + j * 16 + r;
            #pragma unroll
            for (int q = 0; q < 4; ++q) {
                const int row = m0 + wr * 64 + i * 16 + g * 4 + q;
                float v = acc[i][j][q];
                if (gcol < 1536) {
                    QKV[(size_t)row * 1536 + gcol] = v;
                } else if (gcol < 1544) {
                    G[(size_t)row * 8 + (gcol - 1536)] = v;
                }
            }
        }
    }
}

// ---------------------------------------------------------------------------
// Tail GEMM, 64x128 tile, dbuf + counted vmcnt(6) + raw barriers (round-9
// measured form) + XCD swizzle (512/1024 blocks, both %8==0).
// EPI 1: +res(x), DynTanh1 -> split h1s; cols<64 also write h2 tail into aux
// EPI 2: gelu(+bias) then DynTanh2 -> split h2s (stride 1152)
// ---------------------------------------------------------------------------
template <int EPI>
__launch_bounds__(256)
__global__ void gemm_tail64(const _Float16* __restrict__ A2, const _Float16* __restrict__ B2,
                            int Kpad, int KT, void* __restrict__ Cout,
                            const float* __restrict__ bias,
                            const float* __restrict__ res,
                            const float* __restrict__ alphap,
                            const float* __restrict__ gamma,
                            const float* __restrict__ beta,
                            const float* __restrict__ a2p,
                            const float* __restrict__ g2,
                            const float* __restrict__ b2,
                            void* __restrict__ aux) {
    __shared__ __align__(16) char lds[49152];      // 2 x (8KB A + 16KB B)

    const int tid = threadIdx.x;
    const int l = tid & 63, w = tid >> 6;
    const int g = l >> 4, r = l & 15;
    const int nwg = gridDim.x * gridDim.y;
    const int orig = blockIdx.y * gridDim.x + blockIdx.x;
    const int wgid = (orig & 7) * (nwg >> 3) + (orig >> 3);
    const int m0 = (wgid / gridDim.x) * 64;
    const int n0 = (wgid % gridDim.x) * 128;
    const int ldA = 2 * Kpad;
    const int srow = l >> 3;
    const int sl = (l & 7) ^ srow;
    const int scol = (sl & 3) * 8 + ((sl >= 4) ? Kpad : 0);
    const int swz = (l & 7) << 4;
    const int koh = (g << 4) ^ swz;
    const int kol = (64 | (g << 4)) ^ swz;

    f32x4 acc[4][2] = {};

    const _Float16* aS = A2 + (size_t)m0 * ldA + scol;
    const _Float16* bS = B2 + (size_t)n0 * ldA + scol;

    auto stage = [&](int buf, int t) {
        const int kk = t * 32;
        char* d = lds + buf * 24576;
        #pragma unroll
        for (int cc = 0; cc < 2; ++cc) {
            int ch = w * 2 + cc;
            gload16(aS + (size_t)(ch * 8 + srow) * ldA + kk, d + ch * 1024);
        }
        #pragma unroll
        for (int cc = 0; cc < 4; ++cc) {
            int ch = w * 4 + cc;
            gload16(bS + (size_t)(ch * 8 + srow) * ldA + kk, d + 8192 + ch * 1024);
        }
    };

    stage(0, 0);
    for (int t = 0; t < KT; ++t) {
        const int cur = t & 1;
        if (t + 1 < KT) {
            stage(cur ^ 1, t + 1);
            asm volatile("s_waitcnt vmcnt(6)" ::: "memory");
        } else {
            asm volatile("s_waitcnt vmcnt(0)" ::: "memory");
        }
        __builtin_amdgcn_s_barrier();
        __builtin_amdgcn_sched_barrier(0);
        const char* Lb = lds + cur * 24576;
        half8 ah[4], bh[2], xf[4];
        #pragma unroll
        for (int i = 0; i < 4; ++i) ah[i] = *(const half8*)(Lb + (i * 16 + r) * 128 + koh);
        #pragma unroll
        for (int j = 0; j < 2; ++j) bh[j] = *(const half8*)(Lb + 8192 + (w * 32 + j * 16 + r) * 128 + koh);
        #pragma unroll
        for (int i = 0; i < 4; ++i)
            #pragma unroll
            for (int j = 0; j < 2; ++j)
                acc[i][j] = __builtin_amdgcn_mfma_f32_16x16x32_f16(ah[i], bh[j], acc[i][j], 0, 0, 0);
        #pragma unroll
        for (int j = 0; j < 2; ++j) xf[j] = *(const half8*)(Lb + 8192 + (w * 32 + j * 16 + r) * 128 + kol);
        #pragma unroll
        for (int i = 0; i < 4; ++i)
            #pragma unroll
            for (int j = 0; j < 2; ++j)
                acc[i][j] = __builtin_amdgcn_mfma_f32_16x16x32_f16(ah[i], xf[j], acc[i][j], 0, 0, 0);
        #pragma unroll
        for (int i = 0; i < 4; ++i) xf[i] = *(const half8*)(Lb + (i * 16 + r) * 128 + kol);
        #pragma unroll
        for (int i = 0; i < 4; ++i)
            #pragma unroll
            for (int j = 0; j < 2; ++j)
                acc[i][j] = __builtin_amdgcn_mfma_f32_16x16x32_f16(xf[i], bh[j], acc[i][j], 0, 0, 0);
        __builtin_amdgcn_s_barrier();
    }

    const float alp = alphap[0];
    #pragma unroll
    for (int i = 0; i < 4; ++i) {
        #pragma unroll
        for (int j = 0; j < 2; ++j) {
            const int gcol = n0 + w * 32 + j * 16 + r;
            #pragma unroll
            for (int q = 0; q < 4; ++q) {
                const int row = m0 + i * 16 + g * 4 + q;
                float v = acc[i][j][q];
                if (EPI == 1) {
                    v += res[(size_t)row * CDIM + gcol];
                    v = tanhf(alp * v) * gamma[gcol] + beta[gcol];
                    _Float16 hi = (_Float16)v;
                    _Float16 lo = (_Float16)(v - (float)hi);
                    _Float16* H = (_Float16*)Cout;
                    H[(size_t)row * 512 + gcol] = hi;
                    H[(size_t)row * 512 + 256 + gcol] = lo;
                    if (gcol < 64) {
                        int tc = 512 + gcol;
                        float tv = 0.f;
                        if (gcol < 20)
                            tv = tanhf(a2p[0] * res[(size_t)row * CDIM + gcol]) * g2[tc] + b2[tc];
                        _Float16 thi = (_Float16)tv;
                        _Float16 tlo = (_Float16)(tv - (float)thi);
                        _Float16* T = (_Float16*)aux;
                        T[(size_t)row * 1152 + tc] = thi;
                        T[(size_t)row * 1152 + 576 + tc] = tlo;
                    }
                } else {
                    v = gelu_tanh(v + bias[gcol]);
                    v = tanhf(alp * v) * gamma[gcol] + beta[gcol];
                    _Float16 hi = (_Float16)v;
                    _Float16 lo = (_Float16)(v - (float)hi);
                    _Float16* H = (_Float16*)Cout;
                    H[(size_t)row * 1152 + gcol] = hi;
                    H[(size_t)row * 1152 + 576 + gcol] = lo;
                }
            }
        }
    }
}

// ---------------------------------------------------------------------------
// Wout GEMM with fused VQ + loss atomic. NEW: 32-row tiles, 512 blocks = 2/CU
// (round-8 lesson: 1 block/CU has no co-residency to hide stage stalls).
// Same kt-order / 3-pass chain per output element -> bitwise-identical z.
// ---------------------------------------------------------------------------
__launch_bounds__(256)
__global__ void gemm_out_vq(const _Float16* __restrict__ A2, const _Float16* __restrict__ B2,
                            const float* __restrict__ bout, const float* __restrict__ cb,
                            float* __restrict__ outZ, float* __restrict__ outLoss) {
    __shared__ __align__(16) char lds[26624];      // stage dbuf 2x12KB; then zL|cbL
    __shared__ float psum[32];
    float* zL  = (float*)lds;                      // [32][68] = 8704 B
    float* cbL = (float*)(lds + 8704);             // [64][68], col 64 = ||cb||^2

    const int tid = threadIdx.x;
    const int l = tid & 63, w = tid >> 6;
    const int g = l >> 4, r = l & 15;
    const int wr = w >> 1, wc = w & 1;
    const int m0 = blockIdx.x * 32;
    const int Kpad = 576;
    const int ldA = 1152;
    const int srow = l >> 3;
    const int sl = (l & 7) ^ srow;
    const int scol = (sl & 3) * 8 + ((sl >= 4) ? Kpad : 0);
    const int swz = (l & 7) << 4;
    const int aBase = (wr * 16 + r) * 128;
    const int bBase = 4096 + (wc * 32 + r) * 128;
    const int koh = (g << 4) ^ swz;
    const int kol = (64 | (g << 4)) ^ swz;

    f32x4 acc[2] = {};

    const _Float16* aS = A2 + (size_t)m0 * ldA + scol;
    const _Float16* bS = B2 + scol;

    auto stage = [&](int buf, int t) {
        const int kk = t * 32;
        char* d0 = lds + buf * 12288;
        gload16(aS + (size_t)(w * 8 + srow) * ldA + kk, d0 + w * 1024);        // A 4KB
        #pragma unroll
        for (int cc = 0; cc < 2; ++cc) {                                       // B 8KB
            int ch = w * 2 + cc;
            gload16(bS + (size_t)(ch * 8 + srow) * ldA + kk, d0 + 4096 + ch * 1024);
        }
    };

    stage(0, 0);
    for (int t = 0; t < 18; ++t) {
        const int cur = t & 1;
        if (t + 1 < 18) {
            stage(cur ^ 1, t + 1);
            asm volatile("s_waitcnt vmcnt(3)" ::: "memory");
        } else {
            asm volatile("s_waitcnt vmcnt(0)" ::: "memory");
        }
        __builtin_amdgcn_s_barrier();
        __builtin_amdgcn_sched_barrier(0);
        const char* Lb = lds + cur * 12288;
        half8 ah, al, bh[2], xf[2];
        ah = *(const half8*)(Lb + aBase + koh);
        bh[0] = *(const half8*)(Lb + bBase + koh);
        bh[1] = *(const half8*)(Lb + bBase + 2048 + koh);
        acc[0] = __builtin_amdgcn_mfma_f32_16x16x32_f16(ah, bh[0], acc[0], 0, 0, 0);
        acc[1] = __builtin_amdgcn_mfma_f32_16x16x32_f16(ah, bh[1], acc[1], 0, 0, 0);
        xf[0] = *(const half8*)(Lb + bBase + kol);
        xf[1] = *(const half8*)(Lb + bBase + 2048 + kol);
        acc[0] = __builtin_amdgcn_mfma_f32_16x16x32_f16(ah, xf[0], acc[0], 0, 0, 0);
        acc[1] = __builtin_amdgcn_mfma_f32_16x16x32_f16(ah, xf[1], acc[1], 0, 0, 0);
        al = *(const half8*)(Lb + aBase + kol);
        acc[0] = __builtin_amdgcn_mfma_f32_16x16x32_f16(al, bh[0], acc[0], 0, 0, 0);
        acc[1] = __builtin_amdgcn_mfma_f32_16x16x32_f16(al, bh[1], acc[1], 0, 0, 0);
        __builtin_amdgcn_s_barrier();
    }

    // z -> zL (staging region dead now)
    #pragma unroll
    for (int j = 0; j < 2; ++j) {
        int col = wc * 32 + j * 16 + r;
        #pragma unroll
        for (int q = 0; q < 4; ++q) {
            int rl = wr * 16 + g * 4 + q;
            zL[rl * 68 + col] = tanhf(gelu_tanh(acc[j][q] + bout[col]));
        }
    }
    for (int i = tid; i < NEMB * OUTD / 4; i += 256) {
        float4 v = ((const float4*)cb)[i];
        int e = (i * 4) >> 6, c0 = (i * 4) & 63;
        cbL[e * 68 + c0 + 0] = v.x; cbL[e * 68 + c0 + 1] = v.y;
        cbL[e * 68 + c0 + 2] = v.z; cbL[e * 68 + c0 + 3] = v.w;
    }
    __syncthreads();
    if (tid < 64) {
        float cc = 0.f;
        #pragma unroll
        for (int d = 0; d < 64; ++d) { float cv = cbL[tid * 68 + d]; cc += cv * cv; }
        cbL[tid * 68 + 64] = cc;
    }
    __syncthreads();

    const int row = tid >> 3, part = tid & 7;     // 8 threads/row, 8 entries each
    float best = 1e30f;
    int bidx = 0;
    for (int e = part * 8; e < part * 8 + 8; ++e) {
        float dot = 0.f;
        #pragma unroll
        for (int d = 0; d < 64; ++d) dot += zL[row * 68 + d] * cbL[e * 68 + d];
        float sc = cbL[e * 68 + 64] - 2.f * dot;
        if (sc < best) { best = sc; bidx = e; }
    }
    #pragma unroll
    for (int m = 1; m <= 4; m <<= 1) {
        float ob = __shfl_xor(best, m, 64);
        int oi = __shfl_xor(bidx, m, 64);
        if (ob < best || (ob == best && oi < bidx)) { best = ob; bidx = oi; }
    }
    float lsum = 0.f;
    #pragma unroll
    for (int u = 0; u < 8; ++u) {
        const int col = part * 8 + u;
        float cv = cbL[bidx * 68 + col];
        outZ[(size_t)(m0 + row) * 64 + col] = cv;
        float df = zL[row * 68 + col] - cv;
        lsum += df * df;
    }
    lsum += __shfl_xor(lsum, 1, 64);
    lsum += __shfl_xor(lsum, 2, 64);
    lsum += __shfl_xor(lsum, 4, 64);
    if (part == 0) psum[row] = lsum;
    __syncthreads();
    if (tid < 32) {
        float v = psum[tid];
        #pragma unroll
        for (int m = 1; m < 32; m <<= 1) v += __shfl_xor(v, m, 64);
        if (tid == 0)
            atomicAdd(outLoss, v * (0.25f / ((float)NPTS * (float)OUTD)));
    }
}

// ---------------------------------------------------------------------------
// merged prep: x2 split, wqkv2 (incl gate cols + zero pad), wo2T, wlin2T,
// wout2T; also zero-inits outLoss
// ---------------------------------------------------------------------------
#define R0SZ (NPTS * CDIM)
#define S1 (1664 * 256)
#define S2 (256 * 576)
#define S3 (512 * 256)
#define S4 (64 * 576)
__global__ void prep(const float* __restrict__ x,
                     const float* __restrict__ Wq, const float* __restrict__ Wk,
                     const float* __restrict__ Wv, const float* __restrict__ w_gate,
                     const float* __restrict__ Wo, const float* __restrict__ Wlin,
                     const float* __restrict__ Wout,
                     _Float16* __restrict__ x2, _Float16* __restrict__ wqkv2,
                     _Float16* __restrict__ wo2, _Float16* __restrict__ wlin2,
                     _Float16* __restrict__ wout2, float* __restrict__ outLoss) {
    if (blockIdx.x == 0 && threadIdx.x == 0) *outLoss = 0.f;
    for (int idx = blockIdx.x * 256 + threadIdx.x; idx < R0SZ + S1 + S2 + S3 + S4;
         idx += gridDim.x * 256) {
        float v; _Float16* dst; size_t o0, o1;
        if (idx < R0SZ) {
            int n = idx >> 8, cc = idx & 255;
            v = x[idx];
            dst = x2; o0 = (size_t)n * 512 + cc; o1 = o0 + 256;
        } else if (idx < R0SZ + S1) {
            int t = idx - R0SZ;
            int j = t >> 8, k = t & 255;
            if (j < 1536) {
                int jm = j & 511;
                const float* W = (j < 512) ? Wq : (j < 1024) ? Wk : Wv;
                v = W[(size_t)k * 512 + jm];
            } else if (j < 1544) {
                v = w_gate[(size_t)k * 8 + (j - 1536)];
            } else {
                v = 0.f;
            }
            dst = wqkv2; o0 = (size_t)j * 512 + k; o1 = o0 + 256;
        } else if (idx < R0SZ + S1 + S2) {
            int t = idx - R0SZ - S1;
            int j = t / 576, k = t - j * 576;
            v = (k < 520) ? Wo[(size_t)k * 256 + j] : 0.f;
            dst = wo2; o0 = (size_t)j * 1152 + k; o1 = o0 + 576;
        } else if (idx < R0SZ + S1 + S2 + S3) {
            int t = idx - R0SZ - S1 - S2;
            int j = t >> 8, k = t & 255;
            v = Wlin[(size_t)k * 512 + j];
            dst = wlin2; o0 = (size_t)j * 512 + k; o1 = o0 + 256;
        } else {
            int t = idx - R0SZ - S1 - S2 - S3;
            int j = t / 576, k = t - j * 576;
            v = (k < 532) ? Wout[(size_t)k * 64 + j] : 0.f;
            dst = wout2; o0 = (size_t)j * 1152 + k; o1 = o0 + 576;
        }
        _Float16 hi = (_Float16)v, lo = (_Float16)(v - (float)hi);
        dst[o0] = hi; dst[o1] = lo;
    }
}

// ---------------------------------------------------------------------------
// Attention (measured-best form, unchanged): one wave per node, lane = h*8+c.
// ---------------------------------------------------------------------------
__launch_bounds__(256)
__global__ void attn_kernel(const float* __restrict__ QKV, const float* __restrict__ G,
                            const float* __restrict__ coors, const int* __restrict__ nbr,
                            const float* __restrict__ Wr1, const float* __restrict__ br1,
                            const float* __restrict__ Wr2, const float* __restrict__ br2,
                            _Float16* __restrict__ att2) {
    __shared__ float unitL[4][8][3];
    __shared__ float distL[4][8];
    __shared__ float radH[4][8][16];

    const int tid = threadIdx.x;
    const int w = tid >> 6;
    const int lane = tid & 63;
    const int n = blockIdx.x * 4 + w;
    const int h = lane >> 3;
    const int c = lane & 7;

    int jreg[KNBR];
    #pragma unroll
    for (int k = 0; k < KNBR; ++k) jreg[k] = nbr[(size_t)n * KNBR + k];

    if (lane < KNBR) {
        int jj = jreg[lane];
        float rx = coors[(size_t)jj * 3 + 0] - coors[(size_t)n * 3 + 0];
        float ry = coors[(size_t)jj * 3 + 1] - coors[(size_t)n * 3 + 1];
        float rz = coors[(size_t)jj * 3 + 2] - coors[(size_t)n * 3 + 2];
        float d = sqrtf(rx * rx + ry * ry + rz * rz + 1e-8f);
        float inv = 1.0f / d;
        distL[w][lane] = d;
        unitL[w][lane][0] = rx * inv;
        unitL[w][lane][1] = ry * inv;
        unitL[w][lane][2] = rz * inv;
    }

    const float4* qp = (const float4*)(QKV + (size_t)n * 1536 + lane * 8);
    float4 q0 = qp[0], q1 = qp[1];
    float p[KNBR];
    #pragma unroll
    for (int k = 0; k < KNBR; ++k) {
        const float4* kp = (const float4*)(QKV + (size_t)jreg[k] * 1536 + 512 + lane * 8);
        float4 k0 = kp[0], k1 = kp[1];
        p[k] = q0.x * k0.x + q0.y * k0.y + q0.z * k0.z + q0.w * k0.w
             + q1.x * k1.x + q1.y * k1.y + q1.z * k1.z + q1.w * k1.w;
    }
    #pragma unroll
    for (int m = 1; m <= 4; m <<= 1) {
        #pragma unroll
        for (int k = 0; k < KNBR; ++k) p[k] += __shfl_xor(p[k], m, 64);
    }
    __syncthreads();

    #pragma unroll
    for (int rr = 0; rr < 2; ++rr) {
        int idx = lane + rr * 64;
        int k = idx >> 4, i = idx & 15;
        float hv = distL[w][k] * Wr1[i] + br1[i];
        radH[w][k][i] = gelu_tanh(hv);
    }
    __syncthreads();

    float lg[KNBR];
    float b2v = br2[h];
    #pragma unroll
    for (int k = 0; k < KNBR; ++k) {
        float rad = b2v;
        #pragma unroll
        for (int i = 0; i < RHIDD; ++i) rad += radH[w][k][i] * Wr2[i * HEADS + h];
        lg[k] = p[k] * 0.125f + rad;
        if (!(distL[w][k] <= 10.0f)) lg[k] = -1e9f;
    }
    float mx = lg[0];
    #pragma unroll
    for (int k = 1; k < KNBR; ++k) mx = fmaxf(mx, lg[k]);
    float a[KNBR];
    float s = 0.f;
    #pragma unroll
    for (int k = 0; k < KNBR; ++k) { a[k] = expf(lg[k] - mx); s += a[k]; }
    float is = 1.0f / s;
    #pragma unroll
    for (int k = 0; k < KNBR; ++k) a[k] *= is;

    float vx = 0.f, vy = 0.f, vz = 0.f;
    #pragma unroll
    for (int k = 0; k < KNBR; ++k) {
        float gg = G[(size_t)jreg[k] * HEADS + h];
        float ag = a[k] * gg;
        vx += ag * unitL[w][k][0];
        vy += ag * unitL[w][k][1];
        vz += ag * unitL[w][k][2];
    }
    float vn = sqrtf(vx * vx + vy * vy + vz * vz + 1e-8f);

    float4 o0 = {0.f, 0.f, 0.f, 0.f}, o1 = {0.f, 0.f, 0.f, 0.f};
    #pragma unroll
    for (int k = 0; k < KNBR; ++k) {
        const float4* vp = (const float4*)(QKV + (size_t)jreg[k] * 1536 + 1024 + lane * 8);
        float4 v0 = vp[0], v1 = vp[1];
        float ak = a[k];
        o0.x += ak * v0.x; o0.y += ak * v0.y; o0.z += ak * v0.z; o0.w += ak * v0.w;
        o1.x += ak * v1.x; o1.y += ak * v1.y; o1.z += ak * v1.z; o1.w += ak * v1.w;
    }

    float ov[8] = {o0.x, o0.y, o0.z, o0.w, o1.x, o1.y, o1.z, o1.w};
    half8 hi8, lo8;
    #pragma unroll
    for (int t = 0; t < 8; ++t) {
        _Float16 hi = (_Float16)ov[t];
        hi8[t] = hi;
        lo8[t] = (_Float16)(ov[t] - (float)hi);
    }
    *(half8*)(att2 + (size_t)n * 1152 + lane * 8) = hi8;
    *(half8*)(att2 + (size_t)n * 1152 + 576 + lane * 8) = lo8;
    if (c == 0) {
        _Float16 hi = (_Float16)vn, lo = (_Float16)(vn - (float)hi);
        att2[(size_t)n * 1152 + 512 + h] = hi;
        att2[(size_t)n * 1152 + 576 + 512 + h] = lo;
    }
    if (lane < 56) {
        att2[(size_t)n * 1152 + 520 + lane] = (_Float16)0.f;
        att2[(size_t)n * 1152 + 1096 + lane] = (_Float16)0.f;
    }
}

// ---------------------------------------------------------------------------
extern "C" void kernel_launch(void* const* d_in, const int* in_sizes, int n_in,
                              void* d_out, int out_size, void* d_ws, size_t ws_size,
                              hipStream_t stream) {
    const float* x      = (const float*)d_in[0];
    const float* coors  = (const float*)d_in[1];
    const int*   nbr    = (const int*)  d_in[2];
    const float* Wq     = (const float*)d_in[3];
    const float* Wk     = (const float*)d_in[4];
    const float* Wv     = (const float*)d_in[5];
    const float* w_gate = (const float*)d_in[6];
    const float* Wr1    = (const float*)d_in[7];
    const float* br1    = (const float*)d_in[8];
    const float* Wr2    = (const float*)d_in[9];
    const float* br2    = (const float*)d_in[10];
    const float* Wo     = (const float*)d_in[11];
    const float* alpha1 = (const float*)d_in[12];
    const float* gamma1 = (const float*)d_in[13];
    const float* beta1  = (const float*)d_in[14];
    const float* Wlin   = (const float*)d_in[15];
    const float* blin   = (const float*)d_in[16];
    const float* alpha2 = (const float*)d_in[17];
    const float* gamma2 = (const float*)d_in[18];
    const float* beta2  = (const float*)d_in[19];
    const float* Wout   = (const float*)d_in[20];
    const float* bout   = (const float*)d_in[21];
    const float* cb     = (const float*)d_in[22];

    char* wsb = (char*)d_ws;
    float*    QKV   = (float*)   (wsb + 0);          // 100.66 MB, dead after attn
    _Float16* att2  = (_Float16*)(wsb + 100663296);  // 37.75 MB
    _Float16* x2    = (_Float16*)(wsb + 138412032);  // 16.78 MB
    _Float16* wqkv2 = (_Float16*)(wsb + 155189248);  // 1.70 MB
    _Float16* wo2   = (_Float16*)(wsb + 156893184);  // 0.59 MB
    _Float16* wlin2 = (_Float16*)(wsb + 157483008);  // 0.52 MB
    _Float16* wout2 = (_Float16*)(wsb + 158007296);  // 0.15 MB
    float*    G     = (float*)   (wsb + 158154752);  // 0.52 MB
    // aliases inside dead QKV region:
    _Float16* h1s   = (_Float16*)(wsb + 0);          // 16.78 MB (after attn)
    _Float16* h2s   = (_Float16*)(wsb + 20299776);   // 37.75 MB (after attn)

    float* outZ    = (float*)d_out;
    float* outLoss = outZ + (size_t)NPTS * OUTD;

    dim3 blk(256);

    // prep (x split + all weight splits + gate cols + loss zero-init)
    prep<<<dim3(2048), blk, 0, stream>>>(x, Wq, Wk, Wv, w_gate, Wo, Wlin, Wout,
                                         x2, wqkv2, wo2, wlin2, wout2, outLoss);
    // QKV+gate = x @ [Wq|Wk|Wv|w_gate]  (XCD-swizzled)
    gemm_qkv<<<dim3(13, 128), blk, 0, stream>>>(x2, wqkv2, QKV, G);
    // attention
    attn_kernel<<<dim3(NPTS / 4), blk, 0, stream>>>(QKV, G, coors, nbr, Wr1, br1, Wr2, br2, att2);
    // h1 = DynTanh1(x + att@Wo) -> split (64x128 tiles, XCD-swizzled)
    gemm_tail64<1><<<dim3(2, 256), blk, 0, stream>>>(att2, wo2, 576, 18, h1s,
        nullptr, x, alpha1, gamma1, beta1, alpha2, gamma2, beta2, h2s);
    // h2[:, :512] = DynTanh2(gelu(h1@Wlin + blin)) -> split (XCD-swizzled)
    gemm_tail64<2><<<dim3(4, 256), blk, 0, stream>>>(h1s, wlin2, 256, 8, h2s,
        blin, nullptr, alpha2, gamma2, beta2, nullptr, nullptr, nullptr, nullptr);
    // z = tanh(gelu(h2@Wout + bout)) fused with VQ + loss (32-row tiles, 2/CU)
    gemm_out_vq<<<dim3(512), blk, 0, stream>>>(h2s, wout2, bout, cb, outZ, outLoss);
}